// Round 10
// baseline (224.014 us; speedup 1.0000x reference)
//
#include <hip/hip_runtime.h>
#include <stdint.h>

typedef unsigned short u16;
typedef __bf16 bf8 __attribute__((ext_vector_type(8)));
typedef float f4 __attribute__((ext_vector_type(4)));

#define S_ 2048
#define D_ 1024
#define H_ 16
#define HD_ 64
#define M_ 4096

__device__ __forceinline__ u16 f2bf(float f) {
  union { float f; uint32_t u; } v; v.f = f;
  uint32_t u = v.u;
  u += 0x7FFF + ((u >> 16) & 1);   // round-to-nearest-even
  return (u16)(u >> 16);
}

__device__ __forceinline__ void load_lds16(const void* g, void* l) {
  __builtin_amdgcn_global_load_lds(
      (const __attribute__((address_space(1))) void*)g,
      (__attribute__((address_space(3))) void*)l, 16, 0, 0);
}

// stage one 128x32 A-tile + 128x32 B-tile (bf16) into buf (16KB), swizzled
// source so linear gload_lds dest + XOR'd read side are consistent (rule 21).
__device__ __forceinline__ void stage_ab(
    const u16* __restrict__ A, const u16* __restrict__ B,
    int m0, int n0, int kt, u16* buf, int tid) {
  #pragma unroll
  for (int l = 0; l < 4; ++l) {
    int p = l * 256 + tid;          // 0..1023: 16B units; <512 A, >=512 B
    int q = p & 511;
    int row = q >> 2, c = q & 3;
    int clog = c ^ ((row >> 1) & 3);
    const u16* src = (p >> 9)
        ? (B + (size_t)(n0 + row) * 1024 + kt * 32 + clog * 8)
        : (A + (size_t)(m0 + row) * 1024 + kt * 32 + clog * 8);
    load_lds16(src, buf + p * 8);
  }
}

// ---------------- LayerNorm: x f32 -> h bf16 ----------------
__global__ __launch_bounds__(256) void ln_kernel(
    const float* __restrict__ x, const float* __restrict__ gamma,
    const float* __restrict__ beta, u16* __restrict__ hbf) {
  int row = blockIdx.x;
  int tid = threadIdx.x;
  int w = tid >> 6, lane = tid & 63;
  const float* xr = x + (size_t)row * D_;
  float lv[4];
  float s = 0.f;
  #pragma unroll
  for (int i = 0; i < 4; ++i) { lv[i] = xr[tid + i * 256]; s += lv[i]; }
  __shared__ float red[8];
  #pragma unroll
  for (int off = 32; off >= 1; off >>= 1) s += __shfl_xor(s, off);
  if (lane == 0) red[w] = s;
  __syncthreads();
  float mean = (red[0] + red[1] + red[2] + red[3]) * (1.f / D_);
  float vs = 0.f;
  #pragma unroll
  for (int i = 0; i < 4; ++i) { float d = lv[i] - mean; vs += d * d; }
  #pragma unroll
  for (int off = 32; off >= 1; off >>= 1) vs += __shfl_xor(vs, off);
  if (lane == 0) red[4 + w] = vs;
  __syncthreads();
  float var = (red[4] + red[5] + red[6] + red[7]) * (1.f / D_);
  float rstd = rsqrtf(var + 1e-5f);
  #pragma unroll
  for (int i = 0; i < 4; ++i) {
    int col = tid + i * 256;
    float y = (lv[i] - mean) * rstd * gamma[col] + beta[col];
    hbf[(size_t)row * D_ + col] = f2bf(y);
  }
}

// ------ weight convert f32 -> bf16, x4 vectorized (+ Z init: Z[bh][q]=q) ----
__global__ __launch_bounds__(256) void convw_kernel(
    const float* __restrict__ wq, const float* __restrict__ wk,
    const float* __restrict__ wv, const float* __restrict__ wo,
    u16* __restrict__ wqkv, u16* __restrict__ wobf, float* __restrict__ Z) {
  int i4 = blockIdx.x * 256 + threadIdx.x;   // 0 .. 1M-1
  int base = i4 * 4;
  int part = base >> 20;
  int off = base & 0xFFFFF;
  const float* src = part == 0 ? wq : part == 1 ? wk : part == 2 ? wv : wo;
  float4 v = *(const float4*)(src + off);
  ushort4 o;
  o.x = f2bf(v.x); o.y = f2bf(v.y); o.z = f2bf(v.z); o.w = f2bf(v.w);
  if (part < 3) *(ushort4*)(wqkv + base) = o;
  else *(ushort4*)(wobf + off) = o;
  if (i4 < 32 * S_) Z[i4] = (float)(i4 & (S_ - 1));
}

// ---- QKV GEMM: C[4096,3072] = h @ Wqkv^T; 4-deep ring pipeline, BK=32 ----
__global__ __launch_bounds__(256, 2) void gemm_qkv_kernel(
    const u16* __restrict__ A,    // [4096][1024] bf16
    const u16* __restrict__ W,    // [3072][1024] bf16
    const float* __restrict__ bq, const float* __restrict__ bk,
    const float* __restrict__ bv,
    u16* __restrict__ Qb, u16* __restrict__ Kb, float* __restrict__ Vf) {
  __shared__ u16 smem[4 * 8192];   // 4 bufs x (A 8KB + B 8KB)
  const int tid = threadIdx.x;
  const int w = tid >> 6, lane = tid & 63;
  const int wr = w >> 1, wc = w & 1;
  const int lr = lane & 15, hi = lane >> 4;
  const int kswz = (hi ^ ((lr >> 1) & 3)) * 8;   // swizzled 16B slot (in u16)

  // XCD swizzle: 768 blocks, 96/XCD, m-fastest chunks (B-panel reuse in L2)
  int bid = blockIdx.x;
  int swz = (bid & 7) * 96 + (bid >> 3);
  const int m0 = (swz & 31) * 128;
  const int n0 = (swz >> 5) * 128;

  f4 acc[4][4];
  f4 zero = {0.f, 0.f, 0.f, 0.f};
  #pragma unroll
  for (int i = 0; i < 4; ++i)
    #pragma unroll
    for (int j = 0; j < 4; ++j) acc[i][j] = zero;

  stage_ab(A, W, m0, n0, 0, smem, tid);
  stage_ab(A, W, m0, n0, 1, smem + 8192, tid);
  stage_ab(A, W, m0, n0, 2, smem + 16384, tid);

  for (int t = 0; t < 32; ++t) {
    if (t < 30)      asm volatile("s_waitcnt vmcnt(8)\n\ts_barrier" ::: "memory");
    else if (t == 30) asm volatile("s_waitcnt vmcnt(4)\n\ts_barrier" ::: "memory");
    else             asm volatile("s_waitcnt vmcnt(0)\n\ts_barrier" ::: "memory");
    const u16* As = smem + (t & 3) * 8192;
    const u16* Bs = As + 4096;
    bf8 av[4], bvv[4];
    #pragma unroll
    for (int i = 0; i < 4; ++i)
      av[i] = *(const bf8*)&As[(wr * 64 + i * 16 + lr) * 32 + kswz];
    #pragma unroll
    for (int j = 0; j < 4; ++j)
      bvv[j] = *(const bf8*)&Bs[(wc * 64 + j * 16 + lr) * 32 + kswz];
    if (t < 29) stage_ab(A, W, m0, n0, t + 3, smem + ((t + 3) & 3) * 8192, tid);
    __builtin_amdgcn_s_setprio(1);
    #pragma unroll
    for (int i = 0; i < 4; ++i)
      #pragma unroll
      for (int j = 0; j < 4; ++j)
        acc[i][j] = __builtin_amdgcn_mfma_f32_16x16x32_bf16(
            av[i], bvv[j], acc[i][j], 0, 0, 0);
    __builtin_amdgcn_s_setprio(0);
  }

  // epilogue: part is block-uniform (parts 1024-aligned, n0 multiple of 128)
  const int part = n0 >> 10;
  const int colbase = n0 & 1023;
  const float* bias_p = part == 0 ? bq : (part == 1 ? bk : bv);
  if (part < 2) {
    u16* dst = part == 0 ? Qb : Kb;
    #pragma unroll
    for (int i = 0; i < 4; ++i)
      #pragma unroll
      for (int j = 0; j < 4; ++j)
        #pragma unroll
        for (int r = 0; r < 4; ++r) {
          int m = m0 + wr * 64 + i * 16 + hi * 4 + r;
          int col = colbase + wc * 64 + j * 16 + lr;
          float val = acc[i][j][r] + bias_p[col];
          int b = m >> 11, s = m & 2047;
          int hh = col >> 6, d = col & 63;
          dst[((size_t)(b * H_ + hh) * S_ + s) * HD_ + d] = f2bf(val);
        }
  } else {
    #pragma unroll
    for (int i = 0; i < 4; ++i)
      #pragma unroll
      for (int j = 0; j < 4; ++j)
        #pragma unroll
        for (int r = 0; r < 4; ++r) {
          int m = m0 + wr * 64 + i * 16 + hi * 4 + r;
          int col = colbase + wc * 64 + j * 16 + lr;
          float val = acc[i][j][r] + bias_p[col];
          int b = m >> 11, s = m & 2047;
          int hh = col >> 6, d = col & 63;
          Vf[((size_t)(b * H_ + hh) * S_ + s) * HD_ + d] = val;
        }
  }
}

// ------- scores: uniform supertiles (64 q x 256 k), XCD-local bh, atomic Z --
// K-chunk (256x64, 32KB) + Q-strip (64x64, 8KB) staged via global_load_lds in
// FRAGMENT-LINEAR layout: unit u (1KB) holds one wave-fragment at lane*16B,
// per-lane GLOBAL source carries the layout (rule 21) -> conflict-free ds_read.
__global__ __launch_bounds__(256, 4) void scores_z_kernel(
    const u16* __restrict__ Qb, const u16* __restrict__ Kb,
    float* __restrict__ Z, float* __restrict__ Ed) {
  __shared__ u16 sm[20480];           // K: units 0..31 (32KB), Q: units 0..7 (8KB)
  int bid = blockIdx.x;               // 0..4607
  int idx = bid >> 3;                 // 0..575
  int bh = (bid & 7) * 4 + (idx / 144);
  int t = idx - (idx / 144) * 144;    // 0..143
  int g = 0;
  while (true) { int cnt = 4 * (8 - g); if (t < cnt) break; t -= cnt; ++g; }
  const int qb = g * 4 + (t & 3);     // 64-row strip
  const int c = g + (t >> 2);         // 256-col chunk
  const bool diag = (c == g);

  const int tid = threadIdx.x;
  const int w = tid >> 6, lane = tid & 63;
  const int lr = lane & 15, hi = lane >> 4;
  const u16* Qh = Qb + (size_t)bh * S_ * HD_;
  const u16* Kh = Kb + (size_t)bh * S_ * HD_;
  const int q0 = qb * 64;

  // stage K: unit u = tile*2+half; lane l sources K[c*256+tile*16+(l&15)][ (l>>4)*8 + half*32 ]
  #pragma unroll
  for (int ii = 0; ii < 8; ++ii) {
    int unit = ii * 4 + w;            // 0..31
    int tile = unit >> 1, half = unit & 1;
    const u16* src = Kh + (size_t)(c * 256 + tile * 16 + lr) * 64 + hi * 8 + half * 32;
    load_lds16(src, sm + unit * 512 + lane * 8);
  }
  // stage Q: unit u = g2*2+half
  #pragma unroll
  for (int ii = 0; ii < 2; ++ii) {
    int unit = ii * 4 + w;            // 0..7
    int g2 = unit >> 1, half = unit & 1;
    const u16* src = Qh + (size_t)(q0 + g2 * 16 + lr) * 64 + hi * 8 + half * 32;
    load_lds16(src, sm + 16384 + unit * 512 + lane * 8);
  }
  __syncthreads();

  // Q fragments from LDS (conflict-free: lane*16B)
  bf8 a[4][2];
  #pragma unroll
  for (int g2 = 0; g2 < 4; ++g2) {
    a[g2][0] = *(const bf8*)&sm[16384 + (g2 * 2 + 0) * 512 + lane * 8];
    a[g2][1] = *(const bf8*)&sm[16384 + (g2 * 2 + 1) * 512 + lane * 8];
  }

  float zacc[4][4];
  #pragma unroll
  for (int g2 = 0; g2 < 4; ++g2)
    #pragma unroll
    for (int r = 0; r < 4; ++r) zacc[g2][r] = 0.f;

  const float SC = 0.04508422002778011f;   // 1/sqrt(1024) * log2(e)
  #pragma unroll
  for (int i = 0; i < 4; ++i) {
    int tl = w + i * 4;               // local K tile 0..15 (wave-interleaved)
    int kcol = c * 256 + tl * 16 + lr;
    bf8 k0 = *(const bf8*)&sm[(tl * 2 + 0) * 512 + lane * 8];
    bf8 k1 = *(const bf8*)&sm[(tl * 2 + 1) * 512 + lane * 8];
    f4 cc[4];
    #pragma unroll
    for (int g2 = 0; g2 < 4; ++g2) {
      f4 z4 = {0.f, 0.f, 0.f, 0.f};
      z4 = __builtin_amdgcn_mfma_f32_16x16x32_bf16(a[g2][0], k0, z4, 0, 0, 0);
      cc[g2] = __builtin_amdgcn_mfma_f32_16x16x32_bf16(a[g2][1], k1, z4, 0, 0, 0);
    }
    #pragma unroll
    for (int g2 = 0; g2 < 4; ++g2) {
      #pragma unroll
      for (int r = 0; r < 4; ++r) {
        float e = exp2f(cc[g2][r] * SC);
        if (diag) {
          int qrow = q0 + g2 * 16 + hi * 4 + r;
          if (kcol > qrow) {
            zacc[g2][r] += e;
          } else if (kcol == qrow) {
            zacc[g2][r] += e;
            Ed[(size_t)bh * S_ + qrow] = e;
          }
        } else {
          zacc[g2][r] += e;
        }
      }
    }
  }

  __shared__ float Zp[4][64];
  #pragma unroll
  for (int g2 = 0; g2 < 4; ++g2) {
    #pragma unroll
    for (int r = 0; r < 4; ++r) {
      float v = zacc[g2][r];
      v += __shfl_xor(v, 1);
      v += __shfl_xor(v, 2);
      v += __shfl_xor(v, 4);
      v += __shfl_xor(v, 8);
      if (lr == 0) Zp[w][g2 * 16 + hi * 4 + r] = v;
    }
  }
  __syncthreads();
  if (tid < 64) {
    float z = Zp[0][tid] + Zp[1][tid] + Zp[2][tid] + Zp[3][tid];
    atomicAdd(&Z[(size_t)bh * S_ + q0 + tid], z);
  }
}

// ---------------- V prefix-sum chain (16-row chunks) ----------------
#define NC_ 128   // chunks per bh (16 rows each)

__global__ __launch_bounds__(64) void vchunk_kernel(
    const float* __restrict__ Vf, float* __restrict__ csum) {
  int bh = blockIdx.y, c = blockIdx.x;
  int d = threadIdx.x;
  const float* vp = Vf + ((size_t)bh * S_ + c * 16) * HD_ + d;
  float s = 0.f;
  #pragma unroll
  for (int r = 0; r < 16; ++r) s += vp[r * HD_];
  csum[((size_t)bh * NC_ + c) * HD_ + d] = s;
}

// per-bh exclusive scan; all loads issued independently, scan in registers
__global__ __launch_bounds__(256) void vprefix_kernel(float* __restrict__ csum) {
  int bh = blockIdx.x;
  int d = threadIdx.x & 63;
  int qt = threadIdx.x >> 6;
  __shared__ float tot[4][64];
  float v[32];
  #pragma unroll
  for (int c = 0; c < 32; ++c)
    v[c] = csum[((size_t)bh * NC_ + qt * 32 + c) * HD_ + d];
  float run = 0.f;
  #pragma unroll
  for (int c = 0; c < 32; ++c) { float t = v[c]; v[c] = run; run += t; }
  tot[qt][d] = run;
  __syncthreads();
  float off = 0.f;
  #pragma unroll
  for (int p = 0; p < 4; ++p) if (p < qt) off += tot[p][d];
  #pragma unroll
  for (int c = 0; c < 32; ++c)
    csum[((size_t)bh * NC_ + qt * 32 + c) * HD_ + d] = v[c] + off;
}

__global__ __launch_bounds__(64) void attn_out_kernel(
    const float* __restrict__ Vf, const float* __restrict__ csum,
    const float* __restrict__ Z, const float* __restrict__ Ed,
    u16* __restrict__ concat) {
  int bh = blockIdx.y, c = blockIdx.x;
  int d = threadIdx.x;
  int b = bh >> 4, h = bh & 15;
  float run = csum[((size_t)bh * NC_ + c) * HD_ + d];
  #pragma unroll
  for (int r = 0; r < 16; ++r) {
    int s = c * 16 + r;
    size_t vi = ((size_t)bh * S_ + s) * HD_ + d;
    float v = Vf[vi];
    float z = Z[(size_t)bh * S_ + s];
    float e = Ed[(size_t)bh * S_ + s];
    float a = (run + e * v) / z;
    concat[(size_t)(b * S_ + s) * D_ + h * HD_ + d] = f2bf(a);
    run += v;
  }
}

// -- output GEMM: out = x + concat @ wo^T + bo; 4-deep ring pipeline, BK=32 --
__global__ __launch_bounds__(256, 2) void gemm_out_kernel(
    const u16* __restrict__ A,    // concat bf16 [4096][1024]
    const u16* __restrict__ W,    // wo bf16 [1024][1024]
    const float* __restrict__ x, const float* __restrict__ bo,
    float* __restrict__ out) {
  __shared__ u16 smem[4 * 8192];
  const int tid = threadIdx.x;
  const int w = tid >> 6, lane = tid & 63;
  const int wr = w >> 1, wc = w & 1;
  const int lr = lane & 15, hi = lane >> 4;
  const int kswz = (hi ^ ((lr >> 1) & 3)) * 8;

  // XCD swizzle: 256 blocks, 32/XCD
  int bid = blockIdx.x;
  int swz = (bid & 7) * 32 + (bid >> 3);
  const int m0 = (swz & 31) * 128;
  const int n0 = (swz >> 5) * 128;

  f4 acc[4][4];
  f4 zero = {0.f, 0.f, 0.f, 0.f};
  #pragma unroll
  for (int i = 0; i < 4; ++i)
    #pragma unroll
    for (int j = 0; j < 4; ++j) acc[i][j] = zero;

  stage_ab(A, W, m0, n0, 0, smem, tid);
  stage_ab(A, W, m0, n0, 1, smem + 8192, tid);
  stage_ab(A, W, m0, n0, 2, smem + 16384, tid);

  for (int t = 0; t < 32; ++t) {
    if (t < 30)      asm volatile("s_waitcnt vmcnt(8)\n\ts_barrier" ::: "memory");
    else if (t == 30) asm volatile("s_waitcnt vmcnt(4)\n\ts_barrier" ::: "memory");
    else             asm volatile("s_waitcnt vmcnt(0)\n\ts_barrier" ::: "memory");
    const u16* As = smem + (t & 3) * 8192;
    const u16* Bs = As + 4096;
    bf8 av[4], bvv[4];
    #pragma unroll
    for (int i = 0; i < 4; ++i)
      av[i] = *(const bf8*)&As[(wr * 64 + i * 16 + lr) * 32 + kswz];
    #pragma unroll
    for (int j = 0; j < 4; ++j)
      bvv[j] = *(const bf8*)&Bs[(wc * 64 + j * 16 + lr) * 32 + kswz];
    if (t < 29) stage_ab(A, W, m0, n0, t + 3, smem + ((t + 3) & 3) * 8192, tid);
    __builtin_amdgcn_s_setprio(1);
    #pragma unroll
    for (int i = 0; i < 4; ++i)
      #pragma unroll
      for (int j = 0; j < 4; ++j)
        acc[i][j] = __builtin_amdgcn_mfma_f32_16x16x32_bf16(
            av[i], bvv[j], acc[i][j], 0, 0, 0);
    __builtin_amdgcn_s_setprio(0);
  }

  #pragma unroll
  for (int i = 0; i < 4; ++i)
    #pragma unroll
    for (int j = 0; j < 4; ++j)
      #pragma unroll
      for (int r = 0; r < 4; ++r) {
        int m = m0 + wr * 64 + i * 16 + hi * 4 + r;
        int n = n0 + wc * 64 + j * 16 + lr;
        size_t oi = (size_t)m * D_ + n;
        out[oi] = x[oi] + acc[i][j][r] + bo[n];
      }
}

extern "C" void kernel_launch(void* const* d_in, const int* in_sizes, int n_in,
                              void* d_out, int out_size, void* d_ws, size_t ws_size,
                              hipStream_t stream) {
  (void)in_sizes; (void)n_in; (void)out_size; (void)ws_size;
  const float* x     = (const float*)d_in[0];
  const float* wq    = (const float*)d_in[1];
  const float* bq    = (const float*)d_in[2];
  const float* wk    = (const float*)d_in[3];
  const float* bk    = (const float*)d_in[4];
  const float* wv    = (const float*)d_in[5];
  const float* bv    = (const float*)d_in[6];
  const float* wo    = (const float*)d_in[7];
  const float* bo    = (const float*)d_in[8];
  const float* gamma = (const float*)d_in[9];
  const float* beta  = (const float*)d_in[10];
  float* out = (float*)d_out;

  char* ws = (char*)d_ws;
  u16* hbf    = (u16*)(ws);
  u16* wqkv   = (u16*)(ws + (8u << 20));
  u16* wobf   = (u16*)(ws + (14u << 20));
  u16* Qb     = (u16*)(ws + (16u << 20));
  u16* Kb     = (u16*)(ws + (24u << 20));
  float* Vf   = (float*)(ws + (32u << 20));
  float* Z    = (float*)(ws + (48u << 20));
  float* Ed   = (float*)(ws + (48u << 20) + (256u << 10));
  float* csum = (float*)(ws);                 // aliases hbf (dead after QKV GEMM)
  u16* concat = (u16*)(ws + (16u << 20));     // aliases Qb (dead after scores)

  ln_kernel<<<dim3(4096), dim3(256), 0, stream>>>(x, gamma, beta, hbf);
  convw_kernel<<<dim3(4096), dim3(256), 0, stream>>>(wq, wk, wv, wo, wqkv, wobf, Z);
  gemm_qkv_kernel<<<dim3(768), dim3(256), 0, stream>>>(hbf, wqkv, bq, bk, bv,
                                                       Qb, Kb, Vf);
  scores_z_kernel<<<dim3(4608), dim3(256), 0, stream>>>(Qb, Kb, Z, Ed);
  vchunk_kernel<<<dim3(NC_, 32), dim3(64), 0, stream>>>(Vf, csum);
  vprefix_kernel<<<dim3(32), dim3(256), 0, stream>>>(csum);
  attn_out_kernel<<<dim3(NC_, 32), dim3(64), 0, stream>>>(Vf, csum, Z, Ed, concat);
  gemm_out_kernel<<<dim3(256), dim3(256), 0, stream>>>(concat, wobf, x, bo, out);
}

// Round 11
// 209.951 us; speedup vs baseline: 1.0670x; 1.0670x over previous
//
#include <hip/hip_runtime.h>
#include <stdint.h>

typedef unsigned short u16;
typedef __bf16 bf8 __attribute__((ext_vector_type(8)));
typedef float f4 __attribute__((ext_vector_type(4)));

#define S_ 2048
#define D_ 1024
#define H_ 16
#define HD_ 64
#define M_ 4096

__device__ __forceinline__ u16 f2bf(float f) {
  union { float f; uint32_t u; } v; v.f = f;
  uint32_t u = v.u;
  u += 0x7FFF + ((u >> 16) & 1);   // round-to-nearest-even
  return (u16)(u >> 16);
}

__device__ __forceinline__ float fexp2(float x) {
#if __has_builtin(__builtin_amdgcn_exp2f)
  return __builtin_amdgcn_exp2f(x);   // single v_exp_f32
#else
  float r; asm("v_exp_f32 %0, %1" : "=v"(r) : "v"(x)); return r;
#endif
}

__device__ __forceinline__ void load_lds16(const void* g, void* l) {
  __builtin_amdgcn_global_load_lds(
      (const __attribute__((address_space(1))) void*)g,
      (__attribute__((address_space(3))) void*)l, 16, 0, 0);
}

// stage one 128x32 A-tile + 128x32 B-tile (bf16) into buf (16KB), swizzled
// source so linear gload_lds dest + XOR'd read side are consistent (rule 21).
__device__ __forceinline__ void stage_ab(
    const u16* __restrict__ A, const u16* __restrict__ B,
    int m0, int n0, int kt, u16* buf, int tid) {
  #pragma unroll
  for (int l = 0; l < 4; ++l) {
    int p = l * 256 + tid;          // 0..1023: 16B units; <512 A, >=512 B
    int q = p & 511;
    int row = q >> 2, c = q & 3;
    int clog = c ^ ((row >> 1) & 3);
    const u16* src = (p >> 9)
        ? (B + (size_t)(n0 + row) * 1024 + kt * 32 + clog * 8)
        : (A + (size_t)(m0 + row) * 1024 + kt * 32 + clog * 8);
    load_lds16(src, buf + p * 8);
  }
}

// ---------------- LayerNorm: x f32 -> h bf16 ----------------
__global__ __launch_bounds__(256) void ln_kernel(
    const float* __restrict__ x, const float* __restrict__ gamma,
    const float* __restrict__ beta, u16* __restrict__ hbf) {
  int row = blockIdx.x;
  int tid = threadIdx.x;
  int w = tid >> 6, lane = tid & 63;
  const float* xr = x + (size_t)row * D_;
  float lv[4];
  float s = 0.f;
  #pragma unroll
  for (int i = 0; i < 4; ++i) { lv[i] = xr[tid + i * 256]; s += lv[i]; }
  __shared__ float red[8];
  #pragma unroll
  for (int off = 32; off >= 1; off >>= 1) s += __shfl_xor(s, off);
  if (lane == 0) red[w] = s;
  __syncthreads();
  float mean = (red[0] + red[1] + red[2] + red[3]) * (1.f / D_);
  float vs = 0.f;
  #pragma unroll
  for (int i = 0; i < 4; ++i) { float d = lv[i] - mean; vs += d * d; }
  #pragma unroll
  for (int off = 32; off >= 1; off >>= 1) vs += __shfl_xor(vs, off);
  if (lane == 0) red[4 + w] = vs;
  __syncthreads();
  float var = (red[4] + red[5] + red[6] + red[7]) * (1.f / D_);
  float rstd = rsqrtf(var + 1e-5f);
  #pragma unroll
  for (int i = 0; i < 4; ++i) {
    int col = tid + i * 256;
    float y = (lv[i] - mean) * rstd * gamma[col] + beta[col];
    hbf[(size_t)row * D_ + col] = f2bf(y);
  }
}

// ------ weight convert f32 -> bf16, x4 vectorized (+ Z init: Z[bh][q]=q) ----
__global__ __launch_bounds__(256) void convw_kernel(
    const float* __restrict__ wq, const float* __restrict__ wk,
    const float* __restrict__ wv, const float* __restrict__ wo,
    u16* __restrict__ wqkv, u16* __restrict__ wobf, float* __restrict__ Z) {
  int i4 = blockIdx.x * 256 + threadIdx.x;   // 0 .. 1M-1
  int base = i4 * 4;
  int part = base >> 20;
  int off = base & 0xFFFFF;
  const float* src = part == 0 ? wq : part == 1 ? wk : part == 2 ? wv : wo;
  float4 v = *(const float4*)(src + off);
  ushort4 o;
  o.x = f2bf(v.x); o.y = f2bf(v.y); o.z = f2bf(v.z); o.w = f2bf(v.w);
  if (part < 3) *(ushort4*)(wqkv + base) = o;
  else *(ushort4*)(wobf + off) = o;
  if (i4 < 32 * S_) Z[i4] = (float)(i4 & (S_ - 1));
}

// ---- QKV GEMM: C[4096,3072] = h @ Wqkv^T; 4-deep ring pipeline, BK=32 ----
// Q part is PRE-SCALED by log2(e)/32 so scores_z needs only v_exp.
__global__ __launch_bounds__(256, 2) void gemm_qkv_kernel(
    const u16* __restrict__ A,    // [4096][1024] bf16
    const u16* __restrict__ W,    // [3072][1024] bf16
    const float* __restrict__ bq, const float* __restrict__ bk,
    const float* __restrict__ bv,
    u16* __restrict__ Qb, u16* __restrict__ Kb, float* __restrict__ Vf) {
  __shared__ u16 smem[4 * 8192];   // 4 bufs x (A 8KB + B 8KB)
  const int tid = threadIdx.x;
  const int w = tid >> 6, lane = tid & 63;
  const int wr = w >> 1, wc = w & 1;
  const int lr = lane & 15, hi = lane >> 4;
  const int kswz = (hi ^ ((lr >> 1) & 3)) * 8;   // swizzled 16B slot (in u16)

  // XCD swizzle: 768 blocks, 96/XCD, m-fastest chunks (B-panel reuse in L2)
  int bid = blockIdx.x;
  int swz = (bid & 7) * 96 + (bid >> 3);
  const int m0 = (swz & 31) * 128;
  const int n0 = (swz >> 5) * 128;

  f4 acc[4][4];
  f4 zero = {0.f, 0.f, 0.f, 0.f};
  #pragma unroll
  for (int i = 0; i < 4; ++i)
    #pragma unroll
    for (int j = 0; j < 4; ++j) acc[i][j] = zero;

  stage_ab(A, W, m0, n0, 0, smem, tid);
  stage_ab(A, W, m0, n0, 1, smem + 8192, tid);
  stage_ab(A, W, m0, n0, 2, smem + 16384, tid);

  for (int t = 0; t < 32; ++t) {
    if (t < 30)      asm volatile("s_waitcnt vmcnt(8)\n\ts_barrier" ::: "memory");
    else if (t == 30) asm volatile("s_waitcnt vmcnt(4)\n\ts_barrier" ::: "memory");
    else             asm volatile("s_waitcnt vmcnt(0)\n\ts_barrier" ::: "memory");
    const u16* As = smem + (t & 3) * 8192;
    const u16* Bs = As + 4096;
    bf8 av[4], bvv[4];
    #pragma unroll
    for (int i = 0; i < 4; ++i)
      av[i] = *(const bf8*)&As[(wr * 64 + i * 16 + lr) * 32 + kswz];
    #pragma unroll
    for (int j = 0; j < 4; ++j)
      bvv[j] = *(const bf8*)&Bs[(wc * 64 + j * 16 + lr) * 32 + kswz];
    if (t < 29) stage_ab(A, W, m0, n0, t + 3, smem + ((t + 3) & 3) * 8192, tid);
    __builtin_amdgcn_s_setprio(1);
    #pragma unroll
    for (int i = 0; i < 4; ++i)
      #pragma unroll
      for (int j = 0; j < 4; ++j)
        acc[i][j] = __builtin_amdgcn_mfma_f32_16x16x32_bf16(
            av[i], bvv[j], acc[i][j], 0, 0, 0);
    __builtin_amdgcn_s_setprio(0);
  }

  // epilogue: part is block-uniform (parts 1024-aligned, n0 multiple of 128)
  const int part = n0 >> 10;
  const int colbase = n0 & 1023;
  const float SCQ = 0.04508422002778011f;   // log2(e)/sqrt(1024)
  if (part == 0) {
    #pragma unroll
    for (int i = 0; i < 4; ++i)
      #pragma unroll
      for (int j = 0; j < 4; ++j)
        #pragma unroll
        for (int r = 0; r < 4; ++r) {
          int m = m0 + wr * 64 + i * 16 + hi * 4 + r;
          int col = colbase + wc * 64 + j * 16 + lr;
          float val = (acc[i][j][r] + bq[col]) * SCQ;
          int b = m >> 11, s = m & 2047;
          int hh = col >> 6, d = col & 63;
          Qb[((size_t)(b * H_ + hh) * S_ + s) * HD_ + d] = f2bf(val);
        }
  } else if (part == 1) {
    #pragma unroll
    for (int i = 0; i < 4; ++i)
      #pragma unroll
      for (int j = 0; j < 4; ++j)
        #pragma unroll
        for (int r = 0; r < 4; ++r) {
          int m = m0 + wr * 64 + i * 16 + hi * 4 + r;
          int col = colbase + wc * 64 + j * 16 + lr;
          float val = acc[i][j][r] + bk[col];
          int b = m >> 11, s = m & 2047;
          int hh = col >> 6, d = col & 63;
          Kb[((size_t)(b * H_ + hh) * S_ + s) * HD_ + d] = f2bf(val);
        }
  } else {
    #pragma unroll
    for (int i = 0; i < 4; ++i)
      #pragma unroll
      for (int j = 0; j < 4; ++j)
        #pragma unroll
        for (int r = 0; r < 4; ++r) {
          int m = m0 + wr * 64 + i * 16 + hi * 4 + r;
          int col = colbase + wc * 64 + j * 16 + lr;
          float val = acc[i][j][r] + bv[col];
          int b = m >> 11, s = m & 2047;
          int hh = col >> 6, d = col & 63;
          Vf[((size_t)(b * H_ + hh) * S_ + s) * HD_ + d] = val;
        }
  }
}

// ------- scores: uniform supertiles (64 q x 256 k), XCD-local bh, atomic Z --
// Q pre-scaled -> e = 2^cc via single v_exp_f32. Register K/Q loads (round-8
// structure: measured >= LDS-staged variant), branchless diag select.
__global__ __launch_bounds__(256, 4) void scores_z_kernel(
    const u16* __restrict__ Qb, const u16* __restrict__ Kb,
    float* __restrict__ Z, float* __restrict__ Ed) {
  int bid = blockIdx.x;               // 0..4607
  int idx = bid >> 3;                 // 0..575
  int bh = (bid & 7) * 4 + (idx / 144);
  int t = idx - (idx / 144) * 144;    // 0..143
  int g = 0;
  while (true) { int cnt = 4 * (8 - g); if (t < cnt) break; t -= cnt; ++g; }
  const int qb = g * 4 + (t & 3);     // 64-row strip
  const int c = g + (t >> 2);         // 256-col chunk
  const bool diag = (c == g);

  const int tid = threadIdx.x;
  const int w = tid >> 6, lane = tid & 63;
  const int lr = lane & 15, hi = lane >> 4, lkb = hi * 8;
  const u16* Qh = Qb + (size_t)bh * S_ * HD_;
  const u16* Kh = Kb + (size_t)bh * S_ * HD_;
  const int q0 = qb * 64;

  // phase 1: issue ALL 16 independent loads (8 Q + 8 K)
  bf8 a[4][2];
  #pragma unroll
  for (int g2 = 0; g2 < 4; ++g2) {
    a[g2][0] = *(const bf8*)&Qh[(q0 + g2 * 16 + lr) * 64 + lkb];
    a[g2][1] = *(const bf8*)&Qh[(q0 + g2 * 16 + lr) * 64 + 32 + lkb];
  }
  bf8 kb[4][2];
  #pragma unroll
  for (int i = 0; i < 4; ++i) {
    int kt = c * 16 + w + i * 4;      // wave-interleaved: 16 tiles / 4 waves
    kb[i][0] = *(const bf8*)&Kh[(kt * 16 + lr) * 64 + lkb];
    kb[i][1] = *(const bf8*)&Kh[(kt * 16 + lr) * 64 + 32 + lkb];
  }
  __builtin_amdgcn_sched_barrier(0);  // keep loads issued before compute

  float zacc[4][4];
  #pragma unroll
  for (int g2 = 0; g2 < 4; ++g2)
    #pragma unroll
    for (int r = 0; r < 4; ++r) zacc[g2][r] = 0.f;

  #pragma unroll
  for (int i = 0; i < 4; ++i) {
    int kt = c * 16 + w + i * 4;
    int kcol = kt * 16 + lr;
    f4 cc[4];
    #pragma unroll
    for (int g2 = 0; g2 < 4; ++g2) {
      f4 z4 = {0.f, 0.f, 0.f, 0.f};
      z4 = __builtin_amdgcn_mfma_f32_16x16x32_bf16(a[g2][0], kb[i][0], z4, 0, 0, 0);
      cc[g2] = __builtin_amdgcn_mfma_f32_16x16x32_bf16(a[g2][1], kb[i][1], z4, 0, 0, 0);
    }
    if (diag) {
      #pragma unroll
      for (int g2 = 0; g2 < 4; ++g2) {
        #pragma unroll
        for (int r = 0; r < 4; ++r) {
          float e = fexp2(cc[g2][r]);
          int qrow = q0 + g2 * 16 + hi * 4 + r;
          zacc[g2][r] += (kcol >= qrow) ? e : 0.f;
          if (kcol == qrow) Ed[(size_t)bh * S_ + qrow] = e;
        }
      }
    } else {
      #pragma unroll
      for (int g2 = 0; g2 < 4; ++g2) {
        #pragma unroll
        for (int r = 0; r < 4; ++r)
          zacc[g2][r] += fexp2(cc[g2][r]);
      }
    }
  }

  __shared__ float Zp[4][64];
  #pragma unroll
  for (int g2 = 0; g2 < 4; ++g2) {
    #pragma unroll
    for (int r = 0; r < 4; ++r) {
      float v = zacc[g2][r];
      v += __shfl_xor(v, 1);
      v += __shfl_xor(v, 2);
      v += __shfl_xor(v, 4);
      v += __shfl_xor(v, 8);
      if (lr == 0) Zp[w][g2 * 16 + hi * 4 + r] = v;
    }
  }
  __syncthreads();
  if (tid < 64) {
    float z = Zp[0][tid] + Zp[1][tid] + Zp[2][tid] + Zp[3][tid];
    atomicAdd(&Z[(size_t)bh * S_ + q0 + tid], z);
  }
}

// ---------------- V prefix-sum chain (16-row chunks) ----------------
#define NC_ 128   // chunks per bh (16 rows each)

__global__ __launch_bounds__(64) void vchunk_kernel(
    const float* __restrict__ Vf, float* __restrict__ csum) {
  int bh = blockIdx.y, c = blockIdx.x;
  int d = threadIdx.x;
  const float* vp = Vf + ((size_t)bh * S_ + c * 16) * HD_ + d;
  float s = 0.f;
  #pragma unroll
  for (int r = 0; r < 16; ++r) s += vp[r * HD_];
  csum[((size_t)bh * NC_ + c) * HD_ + d] = s;
}

// per-bh exclusive scan; all loads issued independently, scan in registers
__global__ __launch_bounds__(256) void vprefix_kernel(float* __restrict__ csum) {
  int bh = blockIdx.x;
  int d = threadIdx.x & 63;
  int qt = threadIdx.x >> 6;
  __shared__ float tot[4][64];
  float v[32];
  #pragma unroll
  for (int c = 0; c < 32; ++c)
    v[c] = csum[((size_t)bh * NC_ + qt * 32 + c) * HD_ + d];
  float run = 0.f;
  #pragma unroll
  for (int c = 0; c < 32; ++c) { float t = v[c]; v[c] = run; run += t; }
  tot[qt][d] = run;
  __syncthreads();
  float off = 0.f;
  #pragma unroll
  for (int p = 0; p < 4; ++p) if (p < qt) off += tot[p][d];
  #pragma unroll
  for (int c = 0; c < 32; ++c)
    csum[((size_t)bh * NC_ + qt * 32 + c) * HD_ + d] = v[c] + off;
}

__global__ __launch_bounds__(64) void attn_out_kernel(
    const float* __restrict__ Vf, const float* __restrict__ csum,
    const float* __restrict__ Z, const float* __restrict__ Ed,
    u16* __restrict__ concat) {
  int bh = blockIdx.y, c = blockIdx.x;
  int d = threadIdx.x;
  int b = bh >> 4, h = bh & 15;
  float run = csum[((size_t)bh * NC_ + c) * HD_ + d];
  #pragma unroll
  for (int r = 0; r < 16; ++r) {
    int s = c * 16 + r;
    size_t vi = ((size_t)bh * S_ + s) * HD_ + d;
    float v = Vf[vi];
    float z = Z[(size_t)bh * S_ + s];
    float e = Ed[(size_t)bh * S_ + s];
    float a = (run + e * v) / z;
    concat[(size_t)(b * S_ + s) * D_ + h * HD_ + d] = f2bf(a);
    run += v;
  }
}

// -- output GEMM: out = x + concat @ wo^T + bo; 4-deep ring pipeline, BK=32 --
__global__ __launch_bounds__(256, 2) void gemm_out_kernel(
    const u16* __restrict__ A,    // concat bf16 [4096][1024]
    const u16* __restrict__ W,    // wo bf16 [1024][1024]
    const float* __restrict__ x, const float* __restrict__ bo,
    float* __restrict__ out) {
  __shared__ u16 smem[4 * 8192];
  const int tid = threadIdx.x;
  const int w = tid >> 6, lane = tid & 63;
  const int wr = w >> 1, wc = w & 1;
  const int lr = lane & 15, hi = lane >> 4;
  const int kswz = (hi ^ ((lr >> 1) & 3)) * 8;

  // XCD swizzle: 256 blocks, 32/XCD
  int bid = blockIdx.x;
  int swz = (bid & 7) * 32 + (bid >> 3);
  const int m0 = (swz & 31) * 128;
  const int n0 = (swz >> 5) * 128;

  f4 acc[4][4];
  f4 zero = {0.f, 0.f, 0.f, 0.f};
  #pragma unroll
  for (int i = 0; i < 4; ++i)
    #pragma unroll
    for (int j = 0; j < 4; ++j) acc[i][j] = zero;

  stage_ab(A, W, m0, n0, 0, smem, tid);
  stage_ab(A, W, m0, n0, 1, smem + 8192, tid);
  stage_ab(A, W, m0, n0, 2, smem + 16384, tid);

  for (int t = 0; t < 32; ++t) {
    if (t < 30)      asm volatile("s_waitcnt vmcnt(8)\n\ts_barrier" ::: "memory");
    else if (t == 30) asm volatile("s_waitcnt vmcnt(4)\n\ts_barrier" ::: "memory");
    else             asm volatile("s_waitcnt vmcnt(0)\n\ts_barrier" ::: "memory");
    const u16* As = smem + (t & 3) * 8192;
    const u16* Bs = As + 4096;
    bf8 av[4], bvv[4];
    #pragma unroll
    for (int i = 0; i < 4; ++i)
      av[i] = *(const bf8*)&As[(wr * 64 + i * 16 + lr) * 32 + kswz];
    #pragma unroll
    for (int j = 0; j < 4; ++j)
      bvv[j] = *(const bf8*)&Bs[(wc * 64 + j * 16 + lr) * 32 + kswz];
    if (t < 29) stage_ab(A, W, m0, n0, t + 3, smem + ((t + 3) & 3) * 8192, tid);
    __builtin_amdgcn_s_setprio(1);
    #pragma unroll
    for (int i = 0; i < 4; ++i)
      #pragma unroll
      for (int j = 0; j < 4; ++j)
        acc[i][j] = __builtin_amdgcn_mfma_f32_16x16x32_bf16(
            av[i], bvv[j], acc[i][j], 0, 0, 0);
    __builtin_amdgcn_s_setprio(0);
  }

  #pragma unroll
  for (int i = 0; i < 4; ++i)
    #pragma unroll
    for (int j = 0; j < 4; ++j)
      #pragma unroll
      for (int r = 0; r < 4; ++r) {
        int m = m0 + wr * 64 + i * 16 + hi * 4 + r;
        int n = n0 + wc * 64 + j * 16 + lr;
        size_t oi = (size_t)m * D_ + n;
        out[oi] = x[oi] + acc[i][j][r] + bo[n];
      }
}

extern "C" void kernel_launch(void* const* d_in, const int* in_sizes, int n_in,
                              void* d_out, int out_size, void* d_ws, size_t ws_size,
                              hipStream_t stream) {
  (void)in_sizes; (void)n_in; (void)out_size; (void)ws_size;
  const float* x     = (const float*)d_in[0];
  const float* wq    = (const float*)d_in[1];
  const float* bq    = (const float*)d_in[2];
  const float* wk    = (const float*)d_in[3];
  const float* bk    = (const float*)d_in[4];
  const float* wv    = (const float*)d_in[5];
  const float* bv    = (const float*)d_in[6];
  const float* wo    = (const float*)d_in[7];
  const float* bo    = (const float*)d_in[8];
  const float* gamma = (const float*)d_in[9];
  const float* beta  = (const float*)d_in[10];
  float* out = (float*)d_out;

  char* ws = (char*)d_ws;
  u16* hbf    = (u16*)(ws);
  u16* wqkv   = (u16*)(ws + (8u << 20));
  u16* wobf   = (u16*)(ws + (14u << 20));
  u16* Qb     = (u16*)(ws + (16u << 20));
  u16* Kb     = (u16*)(ws + (24u << 20));
  float* Vf   = (float*)(ws + (32u << 20));
  float* Z    = (float*)(ws + (48u << 20));
  float* Ed   = (float*)(ws + (48u << 20) + (256u << 10));
  float* csum = (float*)(ws);                 // aliases hbf (dead after QKV GEMM)
  u16* concat = (u16*)(ws + (16u << 20));     // aliases Qb (dead after scores)

  ln_kernel<<<dim3(4096), dim3(256), 0, stream>>>(x, gamma, beta, hbf);
  convw_kernel<<<dim3(4096), dim3(256), 0, stream>>>(wq, wk, wv, wo, wqkv, wobf, Z);
  gemm_qkv_kernel<<<dim3(768), dim3(256), 0, stream>>>(hbf, wqkv, bq, bk, bv,
                                                       Qb, Kb, Vf);
  scores_z_kernel<<<dim3(4608), dim3(256), 0, stream>>>(Qb, Kb, Z, Ed);
  vchunk_kernel<<<dim3(NC_, 32), dim3(64), 0, stream>>>(Vf, csum);
  vprefix_kernel<<<dim3(32), dim3(256), 0, stream>>>(csum);
  attn_out_kernel<<<dim3(NC_, 32), dim3(64), 0, stream>>>(Vf, csum, Z, Ed, concat);
  gemm_out_kernel<<<dim3(256), dim3(256), 0, stream>>>(concat, wobf, x, bo, out);
}

// Round 12
// 199.759 us; speedup vs baseline: 1.1214x; 1.0510x over previous
//
#include <hip/hip_runtime.h>
#include <stdint.h>

typedef unsigned short u16;
typedef __bf16 bf8 __attribute__((ext_vector_type(8)));
typedef float f4 __attribute__((ext_vector_type(4)));

#define S_ 2048
#define D_ 1024
#define H_ 16
#define HD_ 64
#define M_ 4096

__device__ __forceinline__ u16 f2bf(float f) {
  union { float f; uint32_t u; } v; v.f = f;
  uint32_t u = v.u;
  u += 0x7FFF + ((u >> 16) & 1);   // round-to-nearest-even
  return (u16)(u >> 16);
}

__device__ __forceinline__ float b2f(u16 u) {
  union { uint32_t u; float f; } v; v.u = (uint32_t)u << 16; return v.f;
}

__device__ __forceinline__ float fexp2(float x) {
#if __has_builtin(__builtin_amdgcn_exp2f)
  return __builtin_amdgcn_exp2f(x);   // single v_exp_f32
#else
  float r; asm("v_exp_f32 %0, %1" : "=v"(r) : "v"(x)); return r;
#endif
}

__device__ __forceinline__ void load_lds16(const void* g, void* l) {
  __builtin_amdgcn_global_load_lds(
      (const __attribute__((address_space(1))) void*)g,
      (__attribute__((address_space(3))) void*)l, 16, 0, 0);
}

// stage one 128x32 A-tile + 128x32 B-tile (bf16) into buf (16KB), swizzled
// source so linear gload_lds dest + XOR'd read side are consistent (rule 21).
__device__ __forceinline__ void stage_ab(
    const u16* __restrict__ A, const u16* __restrict__ B,
    int m0, int n0, int kt, u16* buf, int tid) {
  #pragma unroll
  for (int l = 0; l < 4; ++l) {
    int p = l * 256 + tid;          // 0..1023: 16B units; <512 A, >=512 B
    int q = p & 511;
    int row = q >> 2, c = q & 3;
    int clog = c ^ ((row >> 1) & 3);
    const u16* src = (p >> 9)
        ? (B + (size_t)(n0 + row) * 1024 + kt * 32 + clog * 8)
        : (A + (size_t)(m0 + row) * 1024 + kt * 32 + clog * 8);
    load_lds16(src, buf + p * 8);
  }
}

// ------- fused prep: LN (blocks 0..4095) + weight convert (blocks 4096..) ---
__global__ __launch_bounds__(256) void prep_kernel(
    const float* __restrict__ x, const float* __restrict__ gamma,
    const float* __restrict__ beta, u16* __restrict__ hbf,
    const float* __restrict__ wq, const float* __restrict__ wk,
    const float* __restrict__ wv, const float* __restrict__ wo,
    u16* __restrict__ wqkv, u16* __restrict__ wobf, float* __restrict__ Z) {
  int tid = threadIdx.x;
  if (blockIdx.x < 4096) {
    int row = blockIdx.x;
    int w = tid >> 6, lane = tid & 63;
    const float* xr = x + (size_t)row * D_;
    float lv[4];
    float s = 0.f;
    #pragma unroll
    for (int i = 0; i < 4; ++i) { lv[i] = xr[tid + i * 256]; s += lv[i]; }
    __shared__ float red[8];
    #pragma unroll
    for (int off = 32; off >= 1; off >>= 1) s += __shfl_xor(s, off);
    if (lane == 0) red[w] = s;
    __syncthreads();
    float mean = (red[0] + red[1] + red[2] + red[3]) * (1.f / D_);
    float vs = 0.f;
    #pragma unroll
    for (int i = 0; i < 4; ++i) { float d = lv[i] - mean; vs += d * d; }
    #pragma unroll
    for (int off = 32; off >= 1; off >>= 1) vs += __shfl_xor(vs, off);
    if (lane == 0) red[4 + w] = vs;
    __syncthreads();
    float var = (red[4] + red[5] + red[6] + red[7]) * (1.f / D_);
    float rstd = rsqrtf(var + 1e-5f);
    #pragma unroll
    for (int i = 0; i < 4; ++i) {
      int col = tid + i * 256;
      float y = (lv[i] - mean) * rstd * gamma[col] + beta[col];
      hbf[(size_t)row * D_ + col] = f2bf(y);
    }
  } else {
    int i4 = (blockIdx.x - 4096) * 256 + tid;   // 0 .. 1M-1
    int base = i4 * 4;
    int part = base >> 20;
    int off = base & 0xFFFFF;
    const float* src = part == 0 ? wq : part == 1 ? wk : part == 2 ? wv : wo;
    float4 v = *(const float4*)(src + off);
    ushort4 o;
    o.x = f2bf(v.x); o.y = f2bf(v.y); o.z = f2bf(v.z); o.w = f2bf(v.w);
    if (part < 3) *(ushort4*)(wqkv + base) = o;
    else *(ushort4*)(wobf + off) = o;
    if (i4 < 32 * S_) Z[i4] = (float)(i4 & (S_ - 1));
  }
}

// ---- QKV GEMM: C[4096,3072] = h @ Wqkv^T; ring-3 pipeline, BK=32, 48KB ----
// Q pre-scaled by log2(e)/32; Q,K,V all stored bf16 in [B,H,S,HD] layout.
__global__ __launch_bounds__(256, 3) void gemm_qkv_kernel(
    const u16* __restrict__ A,    // [4096][1024] bf16
    const u16* __restrict__ W,    // [3072][1024] bf16
    const float* __restrict__ bq, const float* __restrict__ bk,
    const float* __restrict__ bv,
    u16* __restrict__ Qb, u16* __restrict__ Kb, u16* __restrict__ Vb) {
  __shared__ u16 smem[3 * 8192];   // 3 bufs x (A 8KB + B 8KB)
  const int tid = threadIdx.x;
  const int w = tid >> 6, lane = tid & 63;
  const int wr = w >> 1, wc = w & 1;
  const int lr = lane & 15, hi = lane >> 4;
  const int kswz = (hi ^ ((lr >> 1) & 3)) * 8;   // swizzled 16B slot (in u16)

  // XCD super-chunk: 2x4 XCD grid over 32m x 24n tiles; per-XCD 16m x 6n
  // (A 4MB + B 1.5MB ~ L2-resident), m-fastest inside.
  int bid = blockIdx.x;
  int xcd = bid & 7, i = bid >> 3;        // i 0..95
  int rc = xcd >> 2, cc = xcd & 3;
  const int m0 = (rc * 16 + (i & 15)) * 128;
  const int n0 = (cc * 6 + (i >> 4)) * 128;

  f4 acc[4][4];
  f4 zero = {0.f, 0.f, 0.f, 0.f};
  #pragma unroll
  for (int i2 = 0; i2 < 4; ++i2)
    #pragma unroll
    for (int j = 0; j < 4; ++j) acc[i2][j] = zero;

  stage_ab(A, W, m0, n0, 0, smem, tid);
  stage_ab(A, W, m0, n0, 1, smem + 8192, tid);

  for (int t = 0; t < 32; ++t) {
    if (t < 31) asm volatile("s_waitcnt vmcnt(4)\n\ts_barrier" ::: "memory");
    else        asm volatile("s_waitcnt vmcnt(0)\n\ts_barrier" ::: "memory");
    const u16* As = smem + (t % 3) * 8192;
    const u16* Bs = As + 4096;
    bf8 av[4], bvv[4];
    #pragma unroll
    for (int i2 = 0; i2 < 4; ++i2)
      av[i2] = *(const bf8*)&As[(wr * 64 + i2 * 16 + lr) * 32 + kswz];
    #pragma unroll
    for (int j = 0; j < 4; ++j)
      bvv[j] = *(const bf8*)&Bs[(wc * 64 + j * 16 + lr) * 32 + kswz];
    if (t < 30) stage_ab(A, W, m0, n0, t + 2, smem + ((t + 2) % 3) * 8192, tid);
    __builtin_amdgcn_s_setprio(1);
    #pragma unroll
    for (int i2 = 0; i2 < 4; ++i2)
      #pragma unroll
      for (int j = 0; j < 4; ++j)
        acc[i2][j] = __builtin_amdgcn_mfma_f32_16x16x32_bf16(
            av[i2], bvv[j], acc[i2][j], 0, 0, 0);
    __builtin_amdgcn_s_setprio(0);
  }

  // unified epilogue: part block-uniform; Q scaled, all bf16
  const int part = n0 >> 10;
  const int colbase = n0 & 1023;
  const float SCQ = 0.04508422002778011f;   // log2(e)/sqrt(1024)
  const float* bias_p = part == 0 ? bq : (part == 1 ? bk : bv);
  u16* dst = part == 0 ? Qb : (part == 1 ? Kb : Vb);
  const float scale = part == 0 ? SCQ : 1.f;
  #pragma unroll
  for (int i2 = 0; i2 < 4; ++i2)
    #pragma unroll
    for (int j = 0; j < 4; ++j)
      #pragma unroll
      for (int r = 0; r < 4; ++r) {
        int m = m0 + wr * 64 + i2 * 16 + hi * 4 + r;
        int col = colbase + wc * 64 + j * 16 + lr;
        float val = (acc[i2][j][r] + bias_p[col]) * scale;
        int b = m >> 11, s = m & 2047;
        int hh = col >> 6, d = col & 63;
        dst[((size_t)(b * H_ + hh) * S_ + s) * HD_ + d] = f2bf(val);
      }
}

// ------- scores: uniform supertiles (64 q x 256 k), XCD-local bh, atomic Z --
// Q pre-scaled -> e = 2^cc via single v_exp_f32. Register K/Q loads.
__global__ __launch_bounds__(256, 4) void scores_z_kernel(
    const u16* __restrict__ Qb, const u16* __restrict__ Kb,
    float* __restrict__ Z, float* __restrict__ Ed) {
  int bid = blockIdx.x;               // 0..4607
  int idx = bid >> 3;                 // 0..575
  int bh = (bid & 7) * 4 + (idx / 144);
  int t = idx - (idx / 144) * 144;    // 0..143
  int g = 0;
  while (true) { int cnt = 4 * (8 - g); if (t < cnt) break; t -= cnt; ++g; }
  const int qb = g * 4 + (t & 3);     // 64-row strip
  const int c = g + (t >> 2);         // 256-col chunk
  const bool diag = (c == g);

  const int tid = threadIdx.x;
  const int w = tid >> 6, lane = tid & 63;
  const int lr = lane & 15, hi = lane >> 4, lkb = hi * 8;
  const u16* Qh = Qb + (size_t)bh * S_ * HD_;
  const u16* Kh = Kb + (size_t)bh * S_ * HD_;
  const int q0 = qb * 64;

  bf8 a[4][2];
  #pragma unroll
  for (int g2 = 0; g2 < 4; ++g2) {
    a[g2][0] = *(const bf8*)&Qh[(q0 + g2 * 16 + lr) * 64 + lkb];
    a[g2][1] = *(const bf8*)&Qh[(q0 + g2 * 16 + lr) * 64 + 32 + lkb];
  }
  bf8 kb[4][2];
  #pragma unroll
  for (int i = 0; i < 4; ++i) {
    int kt = c * 16 + w + i * 4;      // wave-interleaved: 16 tiles / 4 waves
    kb[i][0] = *(const bf8*)&Kh[(kt * 16 + lr) * 64 + lkb];
    kb[i][1] = *(const bf8*)&Kh[(kt * 16 + lr) * 64 + 32 + lkb];
  }
  __builtin_amdgcn_sched_barrier(0);

  float zacc[4][4];
  #pragma unroll
  for (int g2 = 0; g2 < 4; ++g2)
    #pragma unroll
    for (int r = 0; r < 4; ++r) zacc[g2][r] = 0.f;

  #pragma unroll
  for (int i = 0; i < 4; ++i) {
    int kt = c * 16 + w + i * 4;
    int kcol = kt * 16 + lr;
    f4 cc[4];
    #pragma unroll
    for (int g2 = 0; g2 < 4; ++g2) {
      f4 z4 = {0.f, 0.f, 0.f, 0.f};
      z4 = __builtin_amdgcn_mfma_f32_16x16x32_bf16(a[g2][0], kb[i][0], z4, 0, 0, 0);
      cc[g2] = __builtin_amdgcn_mfma_f32_16x16x32_bf16(a[g2][1], kb[i][1], z4, 0, 0, 0);
    }
    if (diag) {
      #pragma unroll
      for (int g2 = 0; g2 < 4; ++g2) {
        #pragma unroll
        for (int r = 0; r < 4; ++r) {
          float e = fexp2(cc[g2][r]);
          int qrow = q0 + g2 * 16 + hi * 4 + r;
          zacc[g2][r] += (kcol >= qrow) ? e : 0.f;
          if (kcol == qrow) Ed[(size_t)bh * S_ + qrow] = e;
        }
      }
    } else {
      #pragma unroll
      for (int g2 = 0; g2 < 4; ++g2) {
        #pragma unroll
        for (int r = 0; r < 4; ++r)
          zacc[g2][r] += fexp2(cc[g2][r]);
      }
    }
  }

  __shared__ float Zp[4][64];
  #pragma unroll
  for (int g2 = 0; g2 < 4; ++g2) {
    #pragma unroll
    for (int r = 0; r < 4; ++r) {
      float v = zacc[g2][r];
      v += __shfl_xor(v, 1);
      v += __shfl_xor(v, 2);
      v += __shfl_xor(v, 4);
      v += __shfl_xor(v, 8);
      if (lr == 0) Zp[w][g2 * 16 + hi * 4 + r] = v;
    }
  }
  __syncthreads();
  if (tid < 64) {
    float z = Zp[0][tid] + Zp[1][tid] + Zp[2][tid] + Zp[3][tid];
    atomicAdd(&Z[(size_t)bh * S_ + q0 + tid], z);
  }
}

// ---------------- V prefix-sum chain (16-row chunks, bf16 V) ----------------
#define NC_ 128   // chunks per bh (16 rows each)

__global__ __launch_bounds__(64) void vchunk_kernel(
    const u16* __restrict__ Vb, float* __restrict__ csum) {
  int bh = blockIdx.y, c = blockIdx.x;
  int d = threadIdx.x;
  const u16* vp = Vb + ((size_t)bh * S_ + c * 16) * HD_ + d;
  float s = 0.f;
  #pragma unroll
  for (int r = 0; r < 16; ++r) s += b2f(vp[r * HD_]);
  csum[((size_t)bh * NC_ + c) * HD_ + d] = s;
}

// per-bh exclusive scan; all loads issued independently, scan in registers
__global__ __launch_bounds__(256) void vprefix_kernel(float* __restrict__ csum) {
  int bh = blockIdx.x;
  int d = threadIdx.x & 63;
  int qt = threadIdx.x >> 6;
  __shared__ float tot[4][64];
  float v[32];
  #pragma unroll
  for (int c = 0; c < 32; ++c)
    v[c] = csum[((size_t)bh * NC_ + qt * 32 + c) * HD_ + d];
  float run = 0.f;
  #pragma unroll
  for (int c = 0; c < 32; ++c) { float t = v[c]; v[c] = run; run += t; }
  tot[qt][d] = run;
  __syncthreads();
  float off = 0.f;
  #pragma unroll
  for (int p = 0; p < 4; ++p) if (p < qt) off += tot[p][d];
  #pragma unroll
  for (int c = 0; c < 32; ++c)
    csum[((size_t)bh * NC_ + qt * 32 + c) * HD_ + d] = v[c] + off;
}

__global__ __launch_bounds__(64) void attn_out_kernel(
    const u16* __restrict__ Vb, const float* __restrict__ csum,
    const float* __restrict__ Z, const float* __restrict__ Ed,
    u16* __restrict__ concat) {
  int bh = blockIdx.y, c = blockIdx.x;
  int d = threadIdx.x;
  int b = bh >> 4, h = bh & 15;
  float run = csum[((size_t)bh * NC_ + c) * HD_ + d];
  #pragma unroll
  for (int r = 0; r < 16; ++r) {
    int s = c * 16 + r;
    float v = b2f(Vb[((size_t)bh * S_ + s) * HD_ + d]);
    float z = Z[(size_t)bh * S_ + s];
    float e = Ed[(size_t)bh * S_ + s];
    float a = (run + e * v) / z;
    concat[(size_t)(b * S_ + s) * D_ + h * HD_ + d] = f2bf(a);
    run += v;
  }
}

// -- output GEMM: out = x + concat @ wo^T + bo; ring-3 pipeline, BK=32 --
__global__ __launch_bounds__(256, 3) void gemm_out_kernel(
    const u16* __restrict__ A,    // concat bf16 [4096][1024]
    const u16* __restrict__ W,    // wo bf16 [1024][1024]
    const float* __restrict__ x, const float* __restrict__ bo,
    float* __restrict__ out) {
  __shared__ u16 smem[3 * 8192];
  const int tid = threadIdx.x;
  const int w = tid >> 6, lane = tid & 63;
  const int wr = w >> 1, wc = w & 1;
  const int lr = lane & 15, hi = lane >> 4;
  const int kswz = (hi ^ ((lr >> 1) & 3)) * 8;

  // XCD chunk: 32m x 8n tiles; per-XCD 4m x all-n (A 1MB + B panels ~L2-fit)
  int bid = blockIdx.x;
  int xcd = bid & 7, i = bid >> 3;        // i 0..31
  const int m0 = (xcd * 4 + (i & 3)) * 128;
  const int n0 = (i >> 2) * 128;

  f4 acc[4][4];
  f4 zero = {0.f, 0.f, 0.f, 0.f};
  #pragma unroll
  for (int i2 = 0; i2 < 4; ++i2)
    #pragma unroll
    for (int j = 0; j < 4; ++j) acc[i2][j] = zero;

  stage_ab(A, W, m0, n0, 0, smem, tid);
  stage_ab(A, W, m0, n0, 1, smem + 8192, tid);

  for (int t = 0; t < 32; ++t) {
    if (t < 31) asm volatile("s_waitcnt vmcnt(4)\n\ts_barrier" ::: "memory");
    else        asm volatile("s_waitcnt vmcnt(0)\n\ts_barrier" ::: "memory");
    const u16* As = smem + (t % 3) * 8192;
    const u16* Bs = As + 4096;
    bf8 av[4], bvv[4];
    #pragma unroll
    for (int i2 = 0; i2 < 4; ++i2)
      av[i2] = *(const bf8*)&As[(wr * 64 + i2 * 16 + lr) * 32 + kswz];
    #pragma unroll
    for (int j = 0; j < 4; ++j)
      bvv[j] = *(const bf8*)&Bs[(wc * 64 + j * 16 + lr) * 32 + kswz];
    if (t < 30) stage_ab(A, W, m0, n0, t + 2, smem + ((t + 2) % 3) * 8192, tid);
    __builtin_amdgcn_s_setprio(1);
    #pragma unroll
    for (int i2 = 0; i2 < 4; ++i2)
      #pragma unroll
      for (int j = 0; j < 4; ++j)
        acc[i2][j] = __builtin_amdgcn_mfma_f32_16x16x32_bf16(
            av[i2], bvv[j], acc[i2][j], 0, 0, 0);
    __builtin_amdgcn_s_setprio(0);
  }

  #pragma unroll
  for (int i2 = 0; i2 < 4; ++i2)
    #pragma unroll
    for (int j = 0; j < 4; ++j)
      #pragma unroll
      for (int r = 0; r < 4; ++r) {
        int m = m0 + wr * 64 + i2 * 16 + hi * 4 + r;
        int n = n0 + wc * 64 + j * 16 + lr;
        size_t oi = (size_t)m * D_ + n;
        out[oi] = x[oi] + acc[i2][j][r] + bo[n];
      }
}

extern "C" void kernel_launch(void* const* d_in, const int* in_sizes, int n_in,
                              void* d_out, int out_size, void* d_ws, size_t ws_size,
                              hipStream_t stream) {
  (void)in_sizes; (void)n_in; (void)out_size; (void)ws_size;
  const float* x     = (const float*)d_in[0];
  const float* wq    = (const float*)d_in[1];
  const float* bq    = (const float*)d_in[2];
  const float* wk    = (const float*)d_in[3];
  const float* bk    = (const float*)d_in[4];
  const float* wv    = (const float*)d_in[5];
  const float* bv    = (const float*)d_in[6];
  const float* wo    = (const float*)d_in[7];
  const float* bo    = (const float*)d_in[8];
  const float* gamma = (const float*)d_in[9];
  const float* beta  = (const float*)d_in[10];
  float* out = (float*)d_out;

  char* ws = (char*)d_ws;
  u16* hbf    = (u16*)(ws);
  u16* wqkv   = (u16*)(ws + (8u << 20));
  u16* wobf   = (u16*)(ws + (14u << 20));
  u16* Qb     = (u16*)(ws + (16u << 20));
  u16* Kb     = (u16*)(ws + (24u << 20));
  u16* Vb     = (u16*)(ws + (32u << 20));     // bf16 V (8 MB)
  float* Z    = (float*)(ws + (48u << 20));
  float* Ed   = (float*)(ws + (48u << 20) + (256u << 10));
  float* csum = (float*)(ws);                 // aliases hbf (dead after QKV GEMM)
  u16* concat = (u16*)(ws + (16u << 20));     // aliases Qb (dead after scores)

  prep_kernel<<<dim3(8192), dim3(256), 0, stream>>>(
      x, gamma, beta, hbf, wq, wk, wv, wo, wqkv, wobf, Z);
  gemm_qkv_kernel<<<dim3(768), dim3(256), 0, stream>>>(hbf, wqkv, bq, bk, bv,
                                                       Qb, Kb, Vb);
  scores_z_kernel<<<dim3(4608), dim3(256), 0, stream>>>(Qb, Kb, Z, Ed);
  vchunk_kernel<<<dim3(NC_, 32), dim3(64), 0, stream>>>(Vb, csum);
  vprefix_kernel<<<dim3(32), dim3(256), 0, stream>>>(csum);
  attn_out_kernel<<<dim3(NC_, 32), dim3(64), 0, stream>>>(Vb, csum, Z, Ed, concat);
  gemm_out_kernel<<<dim3(256), dim3(256), 0, stream>>>(concat, wobf, x, bo, out);
}